// Round 12
// baseline (48.331 us; speedup 1.0000x reference)
//
#include <hip/hip_runtime.h>
#include <math.h>

#define BATCH 128
#define NPWM 512
#define LEN 1000
#define NEXT 1024     // 2*NPWM (fwd + revcomp interleaved: f_ext = 2*f + strand)
#define KSLOT 80      // kk padded 19->20, slot = kk*4 + c

typedef __bf16 bf16x4 __attribute__((ext_vector_type(4)));
typedef __bf16 bf16x8 __attribute__((ext_vector_type(8)));
typedef float  f32x16 __attribute__((ext_vector_type(16)));

#define MFMA32(a, b, c) __builtin_amdgcn_mfma_f32_32x32x16_bf16(a, b, c, 0, 0, 0)

// ---- prepack W: (512,4,19) fp32 -> (1024,80) bf16 hi/lo, zeros at pad slots ----
__global__ __launch_bounds__(256)
void prepack_w(const float* __restrict__ w, __bf16* __restrict__ whi, __bf16* __restrict__ wlo)
{
    int idx = blockIdx.x * 256 + threadIdx.x;
    if (idx >= NEXT * KSLOT) return;
    int fe = idx / KSLOT;
    int t  = idx - fe * KSLOT;
    int kk = t >> 2;
    int c  = t & 3;
    int f      = fe >> 1;
    int strand = fe & 1;
    float v = 0.0f;
    if (kk < 19)
        v = strand ? w[f*76 + (3-c)*19 + (18-kk)]   // reverse-complement
                   : w[f*76 + c*19 + kk];
    __bf16 h = (__bf16)v;
    whi[idx] = h;
    wlo[idx] = (__bf16)(v - (float)h);
}

// 16B B-fragment as two conflict-free ds_read_b64
#define LD(EO) __extension__ ({                                          \
    bf16x4 p0_ = *(const bf16x4*)(H + (EO));                             \
    bf16x4 p1_ = *(const bf16x4*)(H + (EO) + 4);                         \
    __builtin_shufflevector(p0_, p1_, 0,1,2,3,4,5,6,7); })

// two position-tiles per pass: 4 independent MFMA chains, issue round-robin
// (dep distance 4 covers ~4x34 cyc of MFMA latency per link)
#define PAIR(IT0, MASKED1)                                               \
  {                                                                      \
    const int e0_ = (IT0)*128 + cgh4;                                    \
    bf16x8 b00 = LD(e0_),       b01 = LD(e0_ + 16),                      \
           b02 = LD(e0_ + 32),  b03 = LD(e0_ + 48), b04 = LD(e0_ + 64);  \
    bf16x8 b10 = LD(e0_ + 128), b11 = LD(e0_ + 144),                     \
           b12 = LD(e0_ + 160), b13 = LD(e0_ + 176), b14 = LD(e0_ + 192);\
    f32x16 h0, l0, h1, l1;                                               \
    h0 = MFMA32(wah[0], b00, zc); l0 = MFMA32(wal[0], b00, zc);          \
    h1 = MFMA32(wah[0], b10, zc); l1 = MFMA32(wal[0], b10, zc);          \
    h0 = MFMA32(wah[1], b01, h0); l0 = MFMA32(wal[1], b01, l0);          \
    h1 = MFMA32(wah[1], b11, h1); l1 = MFMA32(wal[1], b11, l1);          \
    h0 = MFMA32(wah[2], b02, h0); l0 = MFMA32(wal[2], b02, l0);          \
    h1 = MFMA32(wah[2], b12, h1); l1 = MFMA32(wal[2], b12, l1);          \
    h0 = MFMA32(wah[3], b03, h0); l0 = MFMA32(wal[3], b03, l0);          \
    h1 = MFMA32(wah[3], b13, h1); l1 = MFMA32(wal[3], b13, l1);          \
    h0 = MFMA32(wah[4], b04, h0); l0 = MFMA32(wal[4], b04, l0);          \
    h1 = MFMA32(wah[4], b14, h1); l1 = MFMA32(wal[4], b14, l1);          \
    _Pragma("unroll") for (int r = 0; r < 16; ++r)                       \
        m[r] = fmaxf(m[r], h0[r] + l0[r]);                               \
    if (!(MASKED1) || col < 22) {                                        \
      _Pragma("unroll") for (int r = 0; r < 16; ++r)                     \
        m[r] = fmaxf(m[r], h1[r] + l1[r]);                               \
    }                                                                    \
  }

// ---- main: 2-term w-split GEMM, 32x32x16, dep-4 chain interleave, fused max ----
// block = 4 waves = 2 filter-tiles x 2 position-halves; grid = (128,16).
__global__ __launch_bounds__(256, 2)
void pwm_mfma(const float* __restrict__ x,
              const __bf16* __restrict__ whi,
              const __bf16* __restrict__ wlo,
              float* __restrict__ out)
{
    __shared__ __align__(16) __bf16 H[4096];   // bf16(x), [pos][c], pos 0..1023 (tail 0)
    __shared__ float red[2][64];

    const int tid   = threadIdx.x;
    const int b     = blockIdx.x;
    const int by    = blockIdx.y;   // 0..15: which 64 f_ext
    const int lane  = tid & 63;
    const int wave  = tid >> 6;
    const int fhalf = wave & 1;     // which 32-filter tile
    const int wp    = wave >> 1;    // position half
    const int col   = lane & 31;
    const int gh    = lane >> 5;

    // stage bf16(x[b]) position-major [pos][c]; 8B LDS writes, tail zeroed
    for (int i = tid; i < 1024; i += 256) {
        bf16x4 hv;
        #pragma unroll
        for (int c = 0; c < 4; ++c) {
            float v = (i < LEN) ? x[(size_t)b*4000 + c*1000 + i] : 0.0f;
            hv[c] = (__bf16)v;
        }
        *(bf16x4*)(H + i*4) = hv;
    }

    // A fragments (W hi/lo) -> regs: lane holds W[f0+col][k = t*16 + gh*8 + j]
    bf16x8 wah[5], wal[5];
    {
        const int f0 = by*64 + fhalf*32;
        #pragma unroll
        for (int t = 0; t < 5; ++t) {
            const size_t o = (size_t)(f0 + col)*KSLOT + t*16 + gh*8;
            wah[t] = *(const bf16x8*)(whi + o);
            wal[t] = *(const bf16x8*)(wlo + o);
        }
    }
    __syncthreads();

    // B element base: slot k = t*16 + gh*8 + j -> x element (pos + t*4 + 2gh)*4 + c
    const int cgh4 = (col + 2*gh)*4;
    const f32x16 zc = {};   // loop-invariant zero C-in

    f32x16 m;
    #pragma unroll
    for (int r = 0; r < 16; ++r) m[r] = -INFINITY;

    if (wp == 0) {                        // iters 0..15 = 8 pairs
        for (int p = 0; p < 8; ++p) PAIR(2*p, false)
    } else {                              // iters 16..29 = 7 pairs, + masked 30
        for (int p = 0; p < 7; ++p) PAIR(16 + 2*p, false)
        {   // tail iter 30 (dep-2): pos = 960+col, keep pos < 982
            const int e0_ = 30*128 + cgh4;
            bf16x8 b00 = LD(e0_),      b01 = LD(e0_ + 16), b02 = LD(e0_ + 32),
                   b03 = LD(e0_ + 48), b04 = LD(e0_ + 64);
            f32x16 h0, l0;
            h0 = MFMA32(wah[0], b00, zc); l0 = MFMA32(wal[0], b00, zc);
            h0 = MFMA32(wah[1], b01, h0); l0 = MFMA32(wal[1], b01, l0);
            h0 = MFMA32(wah[2], b02, h0); l0 = MFMA32(wal[2], b02, l0);
            h0 = MFMA32(wah[3], b03, h0); l0 = MFMA32(wal[3], b03, l0);
            h0 = MFMA32(wah[4], b04, h0); l0 = MFMA32(wal[4], b04, l0);
            if (col < 22) {
                #pragma unroll
                for (int r = 0; r < 16; ++r) m[r] = fmaxf(m[r], h0[r] + l0[r]);
            }
        }
    }

    // reduce over the 32 position-columns (within each 32-lane half)
    #pragma unroll
    for (int off = 1; off <= 16; off <<= 1)
        #pragma unroll
        for (int r = 0; r < 16; ++r)
            m[r] = fmaxf(m[r], __shfl_xor(m[r], off, 64));

    // D row (f_ext within 32-tile) = (r&3) + 8*(r>>2) + 4*gh
    if (col == 0) {
        #pragma unroll
        for (int r = 0; r < 16; ++r) {
            const int row = (r & 3) + 8*(r >> 2) + 4*gh;
            red[wp][fhalf*32 + row] = m[r];
        }
    }
    __syncthreads();
    if (tid < 32) {   // combine strand pairs (f_ext = 2f, 2f+1) and position halves
        float v0 = fmaxf(red[0][2*tid], red[0][2*tid+1]);
        float v1 = fmaxf(red[1][2*tid], red[1][2*tid+1]);
        out[(size_t)b*NPWM + by*32 + tid] = fmaxf(v0, v1);
    }
}

extern "C" void kernel_launch(void* const* d_in, const int* in_sizes, int n_in,
                              void* d_out, int out_size, void* d_ws, size_t ws_size,
                              hipStream_t stream)
{
    const float* x = (const float*)d_in[0];   // (128, 4, 1000)
    const float* w = (const float*)d_in[1];   // (512, 4, 19)
    float* out = (float*)d_out;               // (128, 512)

    __bf16* whi = (__bf16*)d_ws;              // 1024*80 bf16
    __bf16* wlo = whi + NEXT*KSLOT;

    prepack_w<<<dim3((NEXT*KSLOT + 255)/256), 256, 0, stream>>>(w, whi, wlo);
    pwm_mfma<<<dim3(BATCH, 16), 256, 0, stream>>>(x, whi, wlo, out);
}

// Round 13
// 43.146 us; speedup vs baseline: 1.1202x; 1.1202x over previous
//
#include <hip/hip_runtime.h>
#include <math.h>

#define BATCH 128
#define NPWM 512
#define LEN 1000
#define NEXT 1024     // 2*NPWM (fwd + revcomp interleaved: f_ext = 2*f + strand)
#define KSLOT 96      // kk padded 19->24, slot = kk*4 + c (16x16x32: K mult of 32)

typedef __bf16 bf16x4 __attribute__((ext_vector_type(4)));
typedef __bf16 bf16x8 __attribute__((ext_vector_type(8)));
typedef float  f32x4  __attribute__((ext_vector_type(4)));

#define MFMA16(a, b, c) __builtin_amdgcn_mfma_f32_16x16x32_bf16(a, b, c, 0, 0, 0)

// ---- prepack W: (512,4,19) fp32 -> (1024,96) bf16 hi/lo, zeros at pad slots ----
__global__ __launch_bounds__(256)
void prepack_w(const float* __restrict__ w, __bf16* __restrict__ whi, __bf16* __restrict__ wlo)
{
    int idx = blockIdx.x * 256 + threadIdx.x;
    if (idx >= NEXT * KSLOT) return;
    int fe = idx / KSLOT;
    int t  = idx - fe * KSLOT;
    int kk = t >> 2;
    int c  = t & 3;
    int f      = fe >> 1;
    int strand = fe & 1;
    float v = 0.0f;
    if (kk < 19)
        v = strand ? w[f*76 + (3-c)*19 + (18-kk)]   // reverse-complement
                   : w[f*76 + c*19 + kk];
    __bf16 h = (__bf16)v;
    whi[idx] = h;
    wlo[idx] = (__bf16)(v - (float)h);
}

// ---- main: 2-term w-split GEMM, 16x16x32 (the demonstrated-high-util shape) ----
// block = 4 waves, each wave owns 32 f_ext (fg=2 tiles of 16), scans all positions.
// Per it (2 pos-tiles = 32 pos): 5 ds_read_b128 feed 24 MFMAs in 4 indep dep-6
// chains (adjacent pos-tiles share shifted x-windows: tile0 g0-g2, tile1 g2-g4).
// grid = (128, 8) = 1024 blocks = 4/CU.
__global__ __launch_bounds__(256)
void pwm_mfma(const float* __restrict__ x,
              const __bf16* __restrict__ whi,
              const __bf16* __restrict__ wlo,
              float* __restrict__ out)
{
    __shared__ __align__(16) __bf16 S[8256];   // H0 @0, H1 (shifted +1 pos) @4128
    __shared__ float red[128];

    const int tid   = threadIdx.x;
    const int b     = blockIdx.x;
    const int ftile = blockIdx.y;   // 0..7 (128 f_ext per block)
    const int lane  = tid & 63;
    const int wave  = tid >> 6;
    const int row   = lane & 15;    // position within 16-tile / W k-row
    const int g     = lane >> 4;    // k-eighth group (0..3)

    __bf16* H0 = S;
    __bf16* H1 = S + 4128;          // +32-elem skew: odd-parity banks offset (<=3-way)

    // stage bf16(x[b]) position-major [pos][c] + shifted copy (single pass)
    for (int i = tid; i < 1024; i += 256) {
        bf16x4 hv;
        #pragma unroll
        for (int c = 0; c < 4; ++c) {
            float v = (i < LEN) ? x[(size_t)b*4000 + c*1000 + i] : 0.0f;
            hv[c] = (__bf16)v;
        }
        *(bf16x4*)(H0 + i*4) = hv;
        if (i > 0) *(bf16x4*)(H1 + (i-1)*4) = hv;
    }
    if (tid == 0) { bf16x4 z = {}; *(bf16x4*)(H1 + 1023*4) = z; }

    // A fragments (W hi/lo) -> regs: lane holds W[f0+fg*16+row][k = s*32 + g*8 + j]
    bf16x8 wah[2][3], wal[2][3];
    {
        const int f0 = ftile*128 + wave*32;
        #pragma unroll
        for (int fg = 0; fg < 2; ++fg)
            #pragma unroll
            for (int s = 0; s < 3; ++s) {
                const size_t o = (size_t)(f0 + fg*16 + row)*KSLOT + s*32 + g*8;
                wah[fg][s] = *(const bf16x8*)(whi + o);
                wal[fg][s] = *(const bf16x8*)(wlo + o);
            }
    }
    __syncthreads();

    // B base: pos-tile0 pos = it*32 + row; parity(row) loop-invariant -> 16B reads
    const int lp   = row + 2*g;
    const int par  = row & 1;
    const __bf16* bp = par ? H1 : H0;
    const int eoff = lp*4 - (par ? 4 : 0);

    float m0[4], m1[4];
    #pragma unroll
    for (int r = 0; r < 4; ++r) { m0[r] = -INFINITY; m1[r] = -INFINITY; }
    const f32x4 zc = {};

    for (int it = 0; it < 31; ++it) {
        const int ibase = it*128 + eoff;
        bf16x8 g0 = *(const bf16x8*)(bp + ibase);
        bf16x8 g1 = *(const bf16x8*)(bp + ibase + 32);
        bf16x8 g2 = *(const bf16x8*)(bp + ibase + 64);   // shared: tile0 s2 / tile1 s0
        bf16x8 g3 = *(const bf16x8*)(bp + ibase + 96);
        bf16x8 g4 = *(const bf16x8*)(bp + ibase + 128);

        __builtin_amdgcn_s_setprio(1);
        f32x4 a00 = MFMA16(wah[0][0], g0, zc);
        f32x4 a10 = MFMA16(wah[1][0], g0, zc);
        f32x4 a01 = MFMA16(wah[0][0], g2, zc);
        f32x4 a11 = MFMA16(wah[1][0], g2, zc);
        a00 = MFMA16(wal[0][0], g0, a00);
        a10 = MFMA16(wal[1][0], g0, a10);
        a01 = MFMA16(wal[0][0], g2, a01);
        a11 = MFMA16(wal[1][0], g2, a11);
        a00 = MFMA16(wah[0][1], g1, a00);
        a10 = MFMA16(wah[1][1], g1, a10);
        a01 = MFMA16(wah[0][1], g3, a01);
        a11 = MFMA16(wah[1][1], g3, a11);
        a00 = MFMA16(wal[0][1], g1, a00);
        a10 = MFMA16(wal[1][1], g1, a10);
        a01 = MFMA16(wal[0][1], g3, a01);
        a11 = MFMA16(wal[1][1], g3, a11);
        a00 = MFMA16(wah[0][2], g2, a00);
        a10 = MFMA16(wah[1][2], g2, a10);
        a01 = MFMA16(wah[0][2], g4, a01);
        a11 = MFMA16(wah[1][2], g4, a11);
        a00 = MFMA16(wal[0][2], g2, a00);
        a10 = MFMA16(wal[1][2], g2, a10);
        a01 = MFMA16(wal[0][2], g4, a01);
        a11 = MFMA16(wal[1][2], g4, a11);
        __builtin_amdgcn_s_setprio(0);

        if (it == 30 && row >= 6) {   // tile1 pos = 976+row >= 982: exclude
            #pragma unroll
            for (int r = 0; r < 4; ++r) { a01[r] = -INFINITY; a11[r] = -INFINITY; }
        }
        #pragma unroll
        for (int r = 0; r < 4; ++r) {
            m0[r] = fmaxf(m0[r], fmaxf(a00[r], a01[r]));
            m1[r] = fmaxf(m1[r], fmaxf(a10[r], a11[r]));
        }
    }

    // reduce over the 16 position-columns (lane&15)
    #pragma unroll
    for (int off = 1; off < 16; off <<= 1)
        #pragma unroll
        for (int r = 0; r < 4; ++r) {
            m0[r] = fmaxf(m0[r], __shfl_xor(m0[r], off, 64));
            m1[r] = fmaxf(m1[r], __shfl_xor(m1[r], off, 64));
        }

    // D row (filter within 16-tile) = g*4 + r
    if (row == 0) {
        #pragma unroll
        for (int r = 0; r < 4; ++r) {
            red[wave*32 +      g*4 + r] = m0[r];
            red[wave*32 + 16 + g*4 + r] = m1[r];
        }
    }
    __syncthreads();
    if (tid < 64)   // combine strand pairs (f_ext = 2f, 2f+1)
        out[(size_t)b*NPWM + ftile*64 + tid] = fmaxf(red[2*tid], red[2*tid+1]);
}

extern "C" void kernel_launch(void* const* d_in, const int* in_sizes, int n_in,
                              void* d_out, int out_size, void* d_ws, size_t ws_size,
                              hipStream_t stream)
{
    const float* x = (const float*)d_in[0];   // (128, 4, 1000)
    const float* w = (const float*)d_in[1];   // (512, 4, 19)
    float* out = (float*)d_out;               // (128, 512)

    __bf16* whi = (__bf16*)d_ws;              // 1024*96 bf16
    __bf16* wlo = whi + NEXT*KSLOT;

    prepack_w<<<dim3((NEXT*KSLOT + 255)/256), 256, 0, stream>>>(w, whi, wlo);
    pwm_mfma<<<dim3(BATCH, 8), 256, 0, stream>>>(x, whi, wlo, out);
}

// Round 14
// 42.943 us; speedup vs baseline: 1.1255x; 1.0047x over previous
//
#include <hip/hip_runtime.h>
#include <math.h>

#define BATCH 128
#define NPWM 512
#define LEN 1000
#define NEXT 1024     // 2*NPWM (fwd + revcomp interleaved: f_ext = 2*f + strand)
#define KSLOT 96      // kk padded 19->24, slot = kk*4 + c (16x16x32: K mult of 32)

typedef __bf16 bf16x4 __attribute__((ext_vector_type(4)));
typedef __bf16 bf16x8 __attribute__((ext_vector_type(8)));
typedef float  f32x4  __attribute__((ext_vector_type(4)));

#define MFMA16(a, b, c) __builtin_amdgcn_mfma_f32_16x16x32_bf16(a, b, c, 0, 0, 0)

// ---- prepack W: (512,4,19) fp32 -> (1024,96) bf16 hi/lo, zeros at pad slots ----
__global__ __launch_bounds__(256)
void prepack_w(const float* __restrict__ w, __bf16* __restrict__ whi, __bf16* __restrict__ wlo)
{
    int idx = blockIdx.x * 256 + threadIdx.x;
    if (idx >= NEXT * KSLOT) return;
    int fe = idx / KSLOT;
    int t  = idx - fe * KSLOT;
    int kk = t >> 2;
    int c  = t & 3;
    int f      = fe >> 1;
    int strand = fe & 1;
    float v = 0.0f;
    if (kk < 19)
        v = strand ? w[f*76 + (3-c)*19 + (18-kk)]   // reverse-complement
                   : w[f*76 + c*19 + kk];
    __bf16 h = (__bf16)v;
    whi[idx] = h;
    wlo[idx] = (__bf16)(v - (float)h);
}

// 16B B-fragment as two naturally-8B-aligned ds_read_b64 (conflict-free, R4/R7)
#define LDB(EO) __extension__ ({                                         \
    bf16x4 p0_ = *(const bf16x4*)(H + (EO));                             \
    bf16x4 p1_ = *(const bf16x4*)(H + (EO) + 4);                         \
    __builtin_shufflevector(p0_, p1_, 0,1,2,3,4,5,6,7); })

// one pass over 2 position-tiles (32 pos): 5 shared B-frags feed 24 MFMAs in
// 4 independent dep-6 chains (tile0 uses g0-g2, tile1 g2-g4).
#define KITER(IT)                                                        \
  {                                                                      \
    const int o_ = (IT)*128 + base;                                      \
    bf16x8 g0 = LDB(o_),      g1 = LDB(o_ + 32), g2 = LDB(o_ + 64),      \
           g3 = LDB(o_ + 96), g4 = LDB(o_ + 128);                        \
    __builtin_amdgcn_s_setprio(1);                                       \
    f32x4 a00 = MFMA16(wah[0][0], g0, zc);                               \
    f32x4 a10 = MFMA16(wah[1][0], g0, zc);                               \
    f32x4 a01 = MFMA16(wah[0][0], g2, zc);                               \
    f32x4 a11 = MFMA16(wah[1][0], g2, zc);                               \
    a00 = MFMA16(wal[0][0], g0, a00);                                    \
    a10 = MFMA16(wal[1][0], g0, a10);                                    \
    a01 = MFMA16(wal[0][0], g2, a01);                                    \
    a11 = MFMA16(wal[1][0], g2, a11);                                    \
    a00 = MFMA16(wah[0][1], g1, a00);                                    \
    a10 = MFMA16(wah[1][1], g1, a10);                                    \
    a01 = MFMA16(wah[0][1], g3, a01);                                    \
    a11 = MFMA16(wah[1][1], g3, a11);                                    \
    a00 = MFMA16(wal[0][1], g1, a00);                                    \
    a10 = MFMA16(wal[1][1], g1, a10);                                    \
    a01 = MFMA16(wal[0][1], g3, a01);                                    \
    a11 = MFMA16(wal[1][1], g3, a11);                                    \
    a00 = MFMA16(wah[0][2], g2, a00);                                    \
    a10 = MFMA16(wah[1][2], g2, a10);                                    \
    a01 = MFMA16(wah[0][2], g4, a01);                                    \
    a11 = MFMA16(wah[1][2], g4, a11);                                    \
    a00 = MFMA16(wal[0][2], g2, a00);                                    \
    a10 = MFMA16(wal[1][2], g2, a10);                                    \
    a01 = MFMA16(wal[0][2], g4, a01);                                    \
    a11 = MFMA16(wal[1][2], g4, a11);                                    \
    __builtin_amdgcn_s_setprio(0);                                       \
    if ((IT) == 30 && row >= 6) {   /* tile1 pos = 976+row >= 982 */     \
      _Pragma("unroll")                                                  \
      for (int r = 0; r < 4; ++r) { a01[r] = -INFINITY; a11[r] = -INFINITY; } \
    }                                                                    \
    _Pragma("unroll")                                                    \
    for (int r = 0; r < 4; ++r) {                                        \
      m0[r] = fmaxf(m0[r], fmaxf(a00[r], a01[r]));                       \
      m1[r] = fmaxf(m1[r], fmaxf(a10[r], a11[r]));                       \
    }                                                                    \
  }

// ---- main: 2-term w-split GEMM, 16x16x32, conflict-free b64 loads, wave
// phase-stagger (anti-convoy: wave w starts its sweep at iter w*8, order is
// free under the position-max). block = 4 waves x 32 f_ext; grid = (128,8).
__global__ __launch_bounds__(256)
void pwm_mfma(const float* __restrict__ x,
              const __bf16* __restrict__ whi,
              const __bf16* __restrict__ wlo,
              float* __restrict__ out)
{
    __shared__ __align__(16) __bf16 H[4096];   // bf16(x), [pos][c], pos 0..1023 (tail 0)
    __shared__ float red[128];

    const int tid   = threadIdx.x;
    const int b     = blockIdx.x;
    const int ftile = blockIdx.y;   // 0..7 (128 f_ext per block)
    const int lane  = tid & 63;
    const int wave  = tid >> 6;
    const int row   = lane & 15;    // position within 16-tile / W k-row
    const int g     = lane >> 4;    // k-eighth group (0..3)

    // stage bf16(x[b]) position-major [pos][c]; tail zeroed
    for (int i = tid; i < 1024; i += 256) {
        bf16x4 hv;
        #pragma unroll
        for (int c = 0; c < 4; ++c) {
            float v = (i < LEN) ? x[(size_t)b*4000 + c*1000 + i] : 0.0f;
            hv[c] = (__bf16)v;
        }
        *(bf16x4*)(H + i*4) = hv;
    }

    // A fragments (W hi/lo) -> regs: lane holds W[f0+fg*16+row][k = s*32 + g*8 + j]
    bf16x8 wah[2][3], wal[2][3];
    {
        const int f0 = ftile*128 + wave*32;
        #pragma unroll
        for (int fg = 0; fg < 2; ++fg)
            #pragma unroll
            for (int s = 0; s < 3; ++s) {
                const size_t o = (size_t)(f0 + fg*16 + row)*KSLOT + s*32 + g*8;
                wah[fg][s] = *(const bf16x8*)(whi + o);
                wal[fg][s] = *(const bf16x8*)(wlo + o);
            }
    }
    __syncthreads();

    // B element base: slot k = s*32 + g*8 + j -> x element (it*32 + row + s*8 + g*2)*4
    const int base = row*4 + g*8;
    const f32x4 zc = {};

    float m0[4], m1[4];
    #pragma unroll
    for (int r = 0; r < 4; ++r) { m0[r] = -INFINITY; m1[r] = -INFINITY; }

    const int p0 = wave * 8;        // per-wave phase offset
    for (int it = p0; it < 31; ++it) KITER(it)
    for (int it = 0; it < p0; ++it) KITER(it)

    // reduce over the 16 position-columns (lane&15)
    #pragma unroll
    for (int off = 1; off < 16; off <<= 1)
        #pragma unroll
        for (int r = 0; r < 4; ++r) {
            m0[r] = fmaxf(m0[r], __shfl_xor(m0[r], off, 64));
            m1[r] = fmaxf(m1[r], __shfl_xor(m1[r], off, 64));
        }

    // D row (filter within 16-tile) = g*4 + r
    if (row == 0) {
        #pragma unroll
        for (int r = 0; r < 4; ++r) {
            red[wave*32 +      g*4 + r] = m0[r];
            red[wave*32 + 16 + g*4 + r] = m1[r];
        }
    }
    __syncthreads();
    if (tid < 64)   // combine strand pairs (f_ext = 2f, 2f+1)
        out[(size_t)b*NPWM + ftile*64 + tid] = fmaxf(red[2*tid], red[2*tid+1]);
}

extern "C" void kernel_launch(void* const* d_in, const int* in_sizes, int n_in,
                              void* d_out, int out_size, void* d_ws, size_t ws_size,
                              hipStream_t stream)
{
    const float* x = (const float*)d_in[0];   // (128, 4, 1000)
    const float* w = (const float*)d_in[1];   // (512, 4, 19)
    float* out = (float*)d_out;               // (128, 512)

    __bf16* whi = (__bf16*)d_ws;              // 1024*96 bf16
    __bf16* wlo = whi + NEXT*KSLOT;

    prepack_w<<<dim3((NEXT*KSLOT + 255)/256), 256, 0, stream>>>(w, whi, wlo);
    pwm_mfma<<<dim3(BATCH, 8), 256, 0, stream>>>(x, whi, wlo, out);
}